// Round 15
// baseline (81.606 us; speedup 1.0000x reference)
//
#include <hip/hip_runtime.h>
#include <hip/hip_bf16.h>
#include <math.h>

// Problem dims
#define VOCAB 400000
#define D     300
#define L     2000
#define B     4
#define C1    64
#define C2    128
#define K2    500
#define HID   256
#define NCLS  5
#define NP1   1999   // pooled length after conv1+pool(300)
#define T2    1500   // conv2 out length
#define TPAD  2304   // padded t-length (staging reads up to t0max+639 = 2079)
#define S     8      // cin groups in aT/in1T layout (8 cin each)
#define SP    4      // s-pairs: each k2 block accumulates 2 s-groups
#define CI    8      // cin per group
#define NK2   125    // MFMA K-steps per s-group: k = 4*k2 + g, K=32 per step
#define BN    96     // t per block tile
#define SEGR  640    // staged B rows per s-group (reads need <= 594)
#define NWT   128    // weight-transpose blocks: 8 s * 16 cog(8 co each)
#define NC1B  (B * 500)  // conv1 blocks, 4 windows each

typedef __attribute__((ext_vector_type(8))) short short8v;
typedef __attribute__((ext_vector_type(4))) float f32x4;

__device__ __forceinline__ void gload_lds16(const void* g, void* l) {
    __builtin_amdgcn_global_load_lds(
        (const __attribute__((address_space(1))) void*)g,
        (__attribute__((address_space(3))) void*)l, 16, 0, 0);
}

// ---------------------------------------------------------------------------
// k_prep: fused [weight transpose (LDS-free)] + [embed+conv1+relu+pool].
// (R14-verified, with the strided 301-float4 staging fix.)
// ---------------------------------------------------------------------------
__global__ __launch_bounds__(256) void k_prep(
    const int* __restrict__ x, const float* __restrict__ emb,
    const float* __restrict__ w1, const float* __restrict__ b1,
    const float* __restrict__ w2,
    __hip_bfloat16* __restrict__ in1T, __hip_bfloat16* __restrict__ aT)
{
    __shared__ float smem[1204];
    int bid = blockIdx.x, tid = threadIdx.x;
    if (bid < NWT) {
        // ---- weight transpose: s(8) x cog(16, 8 co each)
        int s = bid >> 4, cog = bid & 15;
        for (int u = tid; u < 4000; u += 256) {
            int co_l = u & 7, kg = u >> 3;       // kg = k2*4+g, 0..499
            int k2 = kg >> 2, g = kg & 3;
            int co = cog * 8 + co_l;
            __hip_bfloat16 tmp[8];
#pragma unroll
            for (int e = 0; e < 8; ++e)
                tmp[e] = __float2bfloat16(
                    w2[((size_t)co * C1 + s * CI + e) * K2 + 4 * k2 + g]);
            *reinterpret_cast<int4*>(
                aT + ((size_t)((s * NK2 + k2) * 4 + g)) * 1024 + (size_t)co * 8) =
                *reinterpret_cast<const int4*>(tmp);
        }
    } else {
        // ---- embed + conv1 + relu + maxpool(300), 4 windows per block
        int blk = bid - NWT;
        int b = blk / 500, pb = blk % 500;
        int p0 = pb * 4;
        float* sig = smem;           // 1204 floats: rows p0..p0+4 x 300 cols
        for (int i = tid; i < 301; i += 256) {   // strided: all 301 float4s
            int rj = i / 75, col = (i % 75) * 4;
            int xi = p0 + rj; if (xi > L - 1) xi = L - 1;     // clamp (guarded use)
            int row = x[b * L + xi];
            *reinterpret_cast<float4*>(sig + 4 * i) =
                *reinterpret_cast<const float4*>(emb + (size_t)row * D + col);
        }
        __syncthreads();
        int c = tid & 63, pg = tid >> 6;
        int p = p0 + pg;
        float wa = w1[c * 3 + 0], wb = w1[c * 3 + 1], wc = w1[c * 3 + 2];
        float bb = b1[c];
        int jb = 300 * pg;
        float m = -INFINITY;
        float4 cur = *reinterpret_cast<float4*>(sig + jb);   // broadcast reads
        for (int st = 0; st < 75; ++st) {
            float4 nxt = *reinterpret_cast<float4*>(sig + jb + 4 * st + 4);
            float xx[8] = {cur.x, cur.y, cur.z, cur.w, nxt.x, nxt.y, nxt.z, nxt.w};
#pragma unroll
            for (int q = 0; q < 4; ++q) {
                float v = fmaf(wc, xx[q + 2], fmaf(wb, xx[q + 1], fmaf(wa, xx[q], bb)));
                m = fmaxf(m, v);
            }
            cur = nxt;
        }
        if (p < NP1) {
            int sg = c >> 3, ci = c & 7;
            in1T[((size_t)(b * S + sg) * TPAD + p) * CI + ci] =
                __float2bfloat16(fmaxf(m, 0.0f));
        }
    }
}

// ---------------------------------------------------------------------------
// k2_mfma: conv2 bf16 MFMA GEMM. Each block accumulates TWO s-groups into the
// same registers; BOTH B-segments staged UPFRONT (single barrier, 20 KB LDS).
// (R12 structure, retried now that the latent k_prep staging bug — the true
// cause of the R10-R13 failures — is fixed.)
// grid 512 = (spair x cog = bid&7, XCD-aligned: 1 MB weights/XCD) x 4b x 16ti,
// 2 blocks/CU (phase-diverse, no barriers in K-loop).
// Block: 64co x 96t; wave 32co x 48t; 6 mfma/step; 250 steps total.
// part partials 8 -> 4: halves k2 store and k2b read traffic (~25 MB saved).
// ---------------------------------------------------------------------------
__global__ __launch_bounds__(256, 2) void k2_mfma(
    const __hip_bfloat16* __restrict__ in1T,
    const __hip_bfloat16* __restrict__ aT,
    float* __restrict__ part)
{
    int bid = blockIdx.x;
    int spair = (bid >> 1) & 3;      // bid&7 -> XCD key
    int cog   = bid & 1;
    int rem = bid >> 3;              // 0..63
    int b = rem >> 4, ti = rem & 15;
    int t0 = ti * BN;
    int s0 = spair * 2;

    __shared__ __align__(16) __hip_bfloat16 seg[2 * SEGR * CI];  // 20480 B

    int tid = threadIdx.x;
    int w = tid >> 6, l = tid & 63;
    int lane16 = l & 15, g = l >> 4;
    int co0w = cog * 64 + (w & 1) * 32;   // block co-half + wave co-quarter
    int tn0  = (w >> 1) * 48;             // 2 t-halves

    // stage BOTH B segments upfront: 1280 rows x 16 B = 5 gloads/thread.
    {
        const char* g0 = (const char*)(in1T + ((size_t)(b * S + s0) * TPAD + t0) * CI);
        const char* g1 = (const char*)(in1T + ((size_t)(b * S + s0 + 1) * TPAD + t0) * CI);
        char* lb = (char*)seg + w * 1024;
#pragma unroll
        for (int r = 0; r < 5; ++r) {
            int u = r * 256 + tid;
            const char* src = (u < SEGR) ? (g0 + (size_t)u * 16)
                                         : (g1 + (size_t)(u - SEGR) * 16);
            gload_lds16(src, lb + r * 4096);
        }
    }
    __syncthreads();   // drains vmcnt(0): both segments in LDS; only barrier

    // per-lane A base: aT[s][k2][g][co128][e8]; frag fa at +fa*128 elements
    const __hip_bfloat16* abase =
        aT + (size_t)s0 * NK2 * 4096 + g * 1024 + (co0w + lane16) * 8;

    f32x4 acc[2][3];
#pragma unroll
    for (int fa = 0; fa < 2; ++fa)
#pragma unroll
        for (int fb = 0; fb < 3; ++fb) acc[fa][fb] = (f32x4){0.f, 0.f, 0.f, 0.f};

#define LOADA(AR, AB, KK)                                                     \
    {                                                                         \
        _Pragma("unroll")                                                     \
        for (int fa = 0; fa < 2; ++fa)                                        \
            AR[fa] = *reinterpret_cast<const short8v*>(                       \
                (AB) + (size_t)(KK) * 4096 + fa * 128);                       \
    }

#define STEP(AR, BB, KK)                                                      \
    {                                                                         \
        short8v bfr[3];                                                       \
        _Pragma("unroll")                                                     \
        for (int fb = 0; fb < 3; ++fb)                                        \
            bfr[fb] = *reinterpret_cast<const short8v*>(                      \
                (BB) + (size_t)(tn0 + fb * 16 + lane16 + 4 * (KK) + g) * 8);  \
        __builtin_amdgcn_s_setprio(1);                                        \
        _Pragma("unroll")                                                     \
        for (int fa = 0; fa < 2; ++fa) {                                      \
            _Pragma("unroll")                                                 \
            for (int fb = 0; fb < 3; ++fb)                                    \
                acc[fa][fb] = __builtin_amdgcn_mfma_f32_16x16x32_bf16(        \
                    AR[fa], bfr[fb], acc[fa][fb], 0, 0, 0);                   \
        }                                                                     \
        __builtin_amdgcn_s_setprio(0);                                        \
    }

#pragma unroll 1
    for (int ph = 0; ph < 2; ++ph) {
        const __hip_bfloat16* ab = abase + (size_t)ph * NK2 * 4096;
        const __hip_bfloat16* bb = seg + (size_t)ph * SEGR * CI;
        short8v a0[2], a1[2];
        LOADA(a0, ab, 0);
        LOADA(a1, ab, 1);
        int k2 = 0;
#pragma unroll 1
        for (; k2 + 3 < NK2; k2 += 2) {  // k2 = 0,2,...,120; exits k2 = 122
            STEP(a0, bb, k2);
            LOADA(a0, ab, k2 + 2);
            STEP(a1, bb, k2 + 1);
            LOADA(a1, ab, k2 + 3);
        }
        STEP(a0, bb, k2);          // 122
        LOADA(a0, ab, k2 + 2);
        STEP(a1, bb, k2 + 1);      // 123
        STEP(a0, bb, k2 + 2);      // 124
    }

#undef LOADA
#undef STEP

    // epilogue: C/D layout col=lane16 (t), row=4*g+r (co within 16)
#pragma unroll
    for (int fa = 0; fa < 2; ++fa) {
#pragma unroll
        for (int fb = 0; fb < 3; ++fb) {
            int t = t0 + tn0 + fb * 16 + lane16;
            if (t < T2) {
                int cob = co0w + fa * 16 + 4 * g;
#pragma unroll
                for (int r = 0; r < 4; ++r)
                    part[((size_t)(spair * B + b) * C2 + cob + r) * T2 + t] =
                        acc[fa][fb][r];
            }
        }
    }
}

// ---------------------------------------------------------------------------
// k2b: sum 4 s-pair partials + bias, relu + maxpool(1500) -> h1[b][co]
// ---------------------------------------------------------------------------
__global__ __launch_bounds__(256) void k2b_pool(
    const float* __restrict__ part, const float* __restrict__ b2,
    float* __restrict__ h1)
{
    int bc = blockIdx.x;             // b*C2 + co
    int b = bc / C2, co = bc % C2;
    int tid = threadIdx.x;
    float m = -INFINITY;
    for (int t4 = tid; t4 < T2 / 4; t4 += 256) {
        float4 sum = {0.f, 0.f, 0.f, 0.f};
#pragma unroll
        for (int sp = 0; sp < SP; ++sp) {
            const float4* p = reinterpret_cast<const float4*>(
                part + ((size_t)(sp * B + b) * C2 + co) * T2);
            float4 v = p[t4];
            sum.x += v.x; sum.y += v.y; sum.z += v.z; sum.w += v.w;
        }
        m = fmaxf(m, fmaxf(fmaxf(sum.x, sum.y), fmaxf(sum.z, sum.w)));
    }
    __shared__ float red[256];
    red[tid] = m;
    __syncthreads();
    for (int st = 128; st > 0; st >>= 1) {
        if (tid < st) red[tid] = fmaxf(red[tid], red[tid + st]);
        __syncthreads();
    }
    if (tid == 0) h1[bc] = fmaxf(red[0] + b2[co], 0.0f);
}

// ---------------------------------------------------------------------------
// k3: lin1 + relu + lin2 + softmax. One block per batch row.
// ---------------------------------------------------------------------------
__global__ __launch_bounds__(256) void k3_head(
    const float* __restrict__ h1,
    const float* __restrict__ wl1, const float* __restrict__ bl1,
    const float* __restrict__ wl2, const float* __restrict__ bl2,
    float* __restrict__ out)
{
    int b = blockIdx.x;
    int tid = threadIdx.x;
    __shared__ float xin[C2];
    __shared__ float hbuf[HID];
    __shared__ float lg[NCLS];
    if (tid < C2) xin[tid] = h1[b * C2 + tid];
    __syncthreads();
    float a = bl1[tid];
    for (int c = 0; c < C2; ++c) a = fmaf(xin[c], wl1[tid * C2 + c], a);
    hbuf[tid] = fmaxf(a, 0.0f);
    __syncthreads();
    if (tid < NCLS) {
        float lv = bl2[tid];
        for (int j = 0; j < HID; ++j) lv = fmaf(hbuf[j], wl2[tid * HID + j], lv);
        lg[tid] = lv;
    }
    __syncthreads();
    if (tid < NCLS) {
        float mx = lg[0];
        for (int i = 1; i < NCLS; ++i) mx = fmaxf(mx, lg[i]);
        float sum = 0.f;
        for (int i = 0; i < NCLS; ++i) sum += expf(lg[i] - mx);
        out[b * NCLS + tid] = expf(lg[tid] - mx) / sum;
    }
}

extern "C" void kernel_launch(void* const* d_in, const int* in_sizes, int n_in,
                              void* d_out, int out_size, void* d_ws, size_t ws_size,
                              hipStream_t stream)
{
    const int*   x   = (const int*)  d_in[0];
    const float* emb = (const float*)d_in[1];
    const float* w1  = (const float*)d_in[2];
    const float* b1  = (const float*)d_in[3];
    const float* w2  = (const float*)d_in[4];
    const float* b2  = (const float*)d_in[5];
    const float* wl1 = (const float*)d_in[6];
    const float* bl1 = (const float*)d_in[7];
    const float* wl2 = (const float*)d_in[8];
    const float* bl2 = (const float*)d_in[9];
    float* out = (float*)d_out;

    // workspace (floats): part 4*4*128*1500 = 3,072,000 | h1 512 |
    // in1T 4*8*2304*8 bf16 = 589824 | aT 8*125*4096 bf16 = 4,096,000
    float* ws   = (float*)d_ws;
    float* part = ws;
    float* h1   = ws + (size_t)SP * B * C2 * T2;
    __hip_bfloat16* in1T = (__hip_bfloat16*)(h1 + 512);
    __hip_bfloat16* aT   = in1T + (size_t)B * S * TPAD * CI;

    hipLaunchKernelGGL(k_prep, dim3(NWT + NC1B), dim3(256), 0, stream,
                       x, emb, w1, b1, w2, in1T, aT);
    hipLaunchKernelGGL(k2_mfma, dim3(512), dim3(256), 0, stream, in1T, aT, part);
    hipLaunchKernelGGL(k2b_pool, dim3(B * C2), dim3(256), 0, stream, part, b2, h1);
    hipLaunchKernelGGL(k3_head, dim3(B), dim3(256), 0, stream,
                       h1, wl1, bl1, wl2, bl2, out);
}